// Round 9
// baseline (390.842 us; speedup 1.0000x reference)
//
#include <hip/hip_runtime.h>

typedef unsigned short u16;
typedef __attribute__((ext_vector_type(8))) short frag8;
typedef __attribute__((ext_vector_type(4))) float f32x4;

static constexpr int C = 768;
static constexpr int F3 = 2304;      // 3*C
static constexpr int MROWS = 32768;  // B*T*H*W
static constexpr float LNEPS = 1e-5f;

__device__ __forceinline__ float bfu2f(u16 u){
  union { unsigned u; float f; } x; x.u = (unsigned)u << 16; return x.f;
}
__device__ __forceinline__ u16 f2bfu(float f){
  union { float f; unsigned u; } x; x.f = f;
  unsigned r = x.u + 0x7fffu + ((x.u >> 16) & 1u);   // RNE bf16
  return (u16)(r >> 16);
}

__device__ __forceinline__ void gload16(const void* g, void* l){
  __builtin_amdgcn_global_load_lds(
      (const __attribute__((address_space(1))) void*)g,
      (__attribute__((address_space(3))) void*)l, 16, 0, 0);
}

// ---------------- fp32 -> bf16 weight conversion ----------------
__global__ __launch_bounds__(256) void cvt_bf16(const float* __restrict__ src,
                                                u16* __restrict__ dst, int n){
  int i = blockIdx.x * 256 + threadIdx.x;
  if (i < n) dst[i] = f2bfu(src[i]);
}

// ---------------- LN1: fp32 x -> bf16 y ----------------
__global__ __launch_bounds__(256) void ln1_kernel(const float* __restrict__ x,
    const float* __restrict__ w, const float* __restrict__ b, u16* __restrict__ y){
  const int lane = threadIdx.x & 63, wid = threadIdx.x >> 6;
  const size_t row = (size_t)blockIdx.x * 4 + wid;
  const float4* xr = reinterpret_cast<const float4*>(x + row * C);
  float v[12];
  #pragma unroll
  for (int j = 0; j < 3; j++){
    float4 t = xr[lane + j*64];
    v[j*4+0]=t.x; v[j*4+1]=t.y; v[j*4+2]=t.z; v[j*4+3]=t.w;
  }
  float s = 0.f, ss = 0.f;
  #pragma unroll
  for (int j = 0; j < 12; j++){ s += v[j]; ss += v[j]*v[j]; }
  #pragma unroll
  for (int o = 32; o; o >>= 1){ s += __shfl_xor(s, o, 64); ss += __shfl_xor(ss, o, 64); }
  const float mu = s * (1.f/768.f);
  const float rs = rsqrtf(ss*(1.f/768.f) - mu*mu + LNEPS);
  ushort4* yr = reinterpret_cast<ushort4*>(y + row * C);
  const float4* wv = reinterpret_cast<const float4*>(w);
  const float4* bv = reinterpret_cast<const float4*>(b);
  #pragma unroll
  for (int j = 0; j < 3; j++){
    float4 wj = wv[lane + j*64], bj = bv[lane + j*64];
    ushort4 o4;
    o4.x = f2bfu((v[j*4+0]-mu)*rs*wj.x + bj.x);
    o4.y = f2bfu((v[j*4+1]-mu)*rs*wj.y + bj.y);
    o4.z = f2bfu((v[j*4+2]-mu)*rs*wj.z + bj.z);
    o4.w = f2bfu((v[j*4+3]-mu)*rs*wj.w + bj.w);
    yr[lane + j*64] = o4;
  }
}

// ---------------- GEMM: C[m,n] = sum_k A[m,k]*B[n,k]  (B^T layout) ----------------
// m201-faithful schedule at K=768: BM=BN=256, BK=64, 12 K-tiles, dbuf-2 x
// (A 32KB + B 32KB) = 128KB. 8 waves (2M x 4N), wave tile 128x64.
// 4 phases/K-tile (kk-half x m-half), each: {<=8 ds_read; stage 1 half of
// tile t+1 (2 gloads; order A-kk0,B-kk0,A-kk1,B-kk1 = consumption order);
// BAR; lgkm(0)+sched_barrier; setprio(1); 16 MFMA; setprio(0); BAR}.
// vmcnt(4) ONLY at P1 and P3 (never 0 in loop). FIFO enumeration: at each
// vmcnt point exactly 8 loads outstanding; vmcnt(4) retires the half-pair the
// NEXT phase's reads need (2-4 phase lead), BEFORE a barrier -> once all waves
// pass that barrier the halves are globally visible.
// R8 BUG / R9 FIX: prologue vmcnt(4) must be followed by s_barrier before the
// loop's first ds_reads (vmcnt is per-wave; tile-0 reads consume other waves'
// staging -> race without the barrier; this was the NaN).
// WAR: stage(t+1) writes buf (t+1)&1, last read at P3(t-1); those reads are
// drained (lgkm(0)) before P3(t-1)'s second barrier, and the stage is issued
// after it -> safe. Wrapped tail (tn->0) keeps vmcnt counts uniform.
// Subtile = 16r x 32k sigma-swizzled (R3-verified): coalesced 64B global
// segments per lane-quad AND conflict-free-per-8-lane ds_read_b128.
// MFMA operands swapped: acc quad = 4 consecutive n -> vectorized stores.
template<int MODE>
__global__ __launch_bounds__(512, 2) void gemm_bt(
    const u16* __restrict__ A, const u16* __restrict__ Bw,
    const float* __restrict__ bias, const float* __restrict__ resid,
    void* __restrict__ Cout, int Ndim, int K)
{
  __shared__ __align__(16) char lds[131072];
  const int tid = threadIdx.x;
  const int lane = tid & 63, wid = tid >> 6;
  const int wm = wid >> 2, wn = wid & 3;        // 2 x 4 wave grid
  const int ntn = Ndim >> 8;
  const int cpx = (int)gridDim.x >> 3;          // bijective XCD swizzle (grid%8==0)
  const int wg = ((int)blockIdx.x & 7) * cpx + ((int)blockIdx.x >> 3);
  const int bm = wg / ntn, bn = wg % ntn;
  const int m0 = bm << 8, n0 = bn << 8;

  // staging source decode (sigma^-1): lane -> (row rr, kchunk qq) of a subtile
  const int rp = lane >> 2;
  const int rr = rp ^ ((rp >> 2) & 1);
  const int qq = (lane & 3) ^ (rr & 3);
  const u16* aS = A  + (size_t)(m0 + rr) * K + qq*8;
  const u16* bS = Bw + (size_t)(n0 + rr) * K + qq*8;
  const size_t rgK = 16 * (size_t)K;

  // fragment read offset within subtile (sigma of (fr,kq)), bytes
  const int fr = lane & 15, kq = lane >> 4;
  const int sig16 = (((fr ^ ((fr >> 2) & 1)) << 2) | (kq ^ (fr & 3))) * 16;

  f32x4 acc[8][4] = {};   // [mf][nf], wave tile 128x64

  // stage half h of K-tile ts: h = 0:A-kk0, 1:B-kk0, 2:A-kk1, 3:B-kk1
  // LDS layout per buf (64KB): A at +0, B at +32768; within op: kk*16384 + rg*1024
  auto stage = [&](int ts, int h){
    const int isB = h & 1, kk = h >> 1;
    char* lb = lds + (ts & 1)*65536 + isB*32768 + kk*16384;
    const u16* s = (isB ? bS : aS) + ts*64 + kk*32;
    gload16(s + (size_t)wid       * rgK, lb + wid*1024);
    gload16(s + (size_t)(wid + 8) * rgK, lb + (wid+8)*1024);
  };

  stage(0,0); stage(0,1); stage(0,2); stage(0,3);        // 8 loads in flight
  asm volatile("s_waitcnt vmcnt(4)" ::: "memory");       // own A-kk0(0),B-kk0(0) landed
  __builtin_amdgcn_s_barrier();                          // R9 FIX: all waves' landed

  for (int t = 0; t < 12; ++t){
    const char* bc = lds + (t & 1)*65536;
    const char* pa = bc + (wm*8)*1024 + sig16;           // A rg = wm*8+mf
    const char* pb = bc + 32768 + (wn*4)*1024 + sig16;   // B rg = wn*4+nf
    int tn = t + 1; if (tn >= 12) tn = 0;                // wrapped tail keeps vmcnt uniform
    frag8 af[4], bf[4];

    // ---------- P0: kk0, m-lo ----------
    #pragma unroll
    for (int i = 0; i < 4; i++) af[i] = *reinterpret_cast<const frag8*>(pa + i*1024);
    #pragma unroll
    for (int j = 0; j < 4; j++) bf[j] = *reinterpret_cast<const frag8*>(pb + j*1024);
    stage(tn, 0);
    __builtin_amdgcn_s_barrier();
    asm volatile("s_waitcnt lgkmcnt(0)" ::: "memory");
    __builtin_amdgcn_sched_barrier(0);
    __builtin_amdgcn_s_setprio(1);
    #pragma unroll
    for (int i = 0; i < 4; i++)
      #pragma unroll
      for (int j = 0; j < 4; j++)
        acc[i][j] = __builtin_amdgcn_mfma_f32_16x16x32_bf16(bf[j], af[i], acc[i][j], 0, 0, 0);
    __builtin_amdgcn_s_setprio(0);
    __builtin_amdgcn_s_barrier();

    // ---------- P1: kk0, m-hi ----------
    #pragma unroll
    for (int i = 0; i < 4; i++) af[i] = *reinterpret_cast<const frag8*>(pa + (4+i)*1024);
    stage(tn, 1);
    asm volatile("s_waitcnt vmcnt(4)" ::: "memory");     // retire A-kk1(t),B-kk1(t)
    __builtin_amdgcn_s_barrier();
    asm volatile("s_waitcnt lgkmcnt(0)" ::: "memory");
    __builtin_amdgcn_sched_barrier(0);
    __builtin_amdgcn_s_setprio(1);
    #pragma unroll
    for (int i = 0; i < 4; i++)
      #pragma unroll
      for (int j = 0; j < 4; j++)
        acc[4+i][j] = __builtin_amdgcn_mfma_f32_16x16x32_bf16(bf[j], af[i], acc[4+i][j], 0, 0, 0);
    __builtin_amdgcn_s_setprio(0);
    __builtin_amdgcn_s_barrier();

    // ---------- P2: kk1, m-lo ----------
    #pragma unroll
    for (int i = 0; i < 4; i++) af[i] = *reinterpret_cast<const frag8*>(pa + 16384 + i*1024);
    #pragma unroll
    for (int j = 0; j < 4; j++) bf[j] = *reinterpret_cast<const frag8*>(pb + 16384 + j*1024);
    stage(tn, 2);
    __builtin_amdgcn_s_barrier();
    asm volatile("s_waitcnt lgkmcnt(0)" ::: "memory");
    __builtin_amdgcn_sched_barrier(0);
    __builtin_amdgcn_s_setprio(1);
    #pragma unroll
    for (int i = 0; i < 4; i++)
      #pragma unroll
      for (int j = 0; j < 4; j++)
        acc[i][j] = __builtin_amdgcn_mfma_f32_16x16x32_bf16(bf[j], af[i], acc[i][j], 0, 0, 0);
    __builtin_amdgcn_s_setprio(0);
    __builtin_amdgcn_s_barrier();

    // ---------- P3: kk1, m-hi ----------
    #pragma unroll
    for (int i = 0; i < 4; i++) af[i] = *reinterpret_cast<const frag8*>(pa + 16384 + (4+i)*1024);
    stage(tn, 3);
    asm volatile("s_waitcnt vmcnt(4)" ::: "memory");     // retire A-kk0(tn),B-kk0(tn)
    __builtin_amdgcn_s_barrier();
    asm volatile("s_waitcnt lgkmcnt(0)" ::: "memory");
    __builtin_amdgcn_sched_barrier(0);
    __builtin_amdgcn_s_setprio(1);
    #pragma unroll
    for (int i = 0; i < 4; i++)
      #pragma unroll
      for (int j = 0; j < 4; j++)
        acc[4+i][j] = __builtin_amdgcn_mfma_f32_16x16x32_bf16(bf[j], af[i], acc[4+i][j], 0, 0, 0);
    __builtin_amdgcn_s_setprio(0);
    __builtin_amdgcn_s_barrier();
  }
  asm volatile("s_waitcnt vmcnt(0)" ::: "memory");       // drain wrapped tail stages

  // epilogue (swapped layout): m = lane&15 (+16mf+128wm), n-quad = (lane>>4)*4 (+16nf+64wn)
  const int em = fr, en = kq * 4;
  float4 bb[4];
  #pragma unroll
  for (int nf = 0; nf < 4; nf++)
    bb[nf] = *reinterpret_cast<const float4*>(bias + n0 + wn*64 + nf*16 + en);

  #pragma unroll
  for (int mf = 0; mf < 8; mf++){
    const size_t m = (size_t)(m0 + wm*128 + mf*16 + em);
    #pragma unroll
    for (int nf = 0; nf < 4; nf++){
      const int n = n0 + wn*64 + nf*16 + en;
      if (MODE == 0){
        ushort4 o4;
        o4.x = f2bfu(acc[mf][nf][0] + bb[nf].x);
        o4.y = f2bfu(acc[mf][nf][1] + bb[nf].y);
        o4.z = f2bfu(acc[mf][nf][2] + bb[nf].z);
        o4.w = f2bfu(acc[mf][nf][3] + bb[nf].w);
        *reinterpret_cast<ushort4*>((u16*)Cout + m * Ndim + n) = o4;
      } else {
        const float4 rr4 = *reinterpret_cast<const float4*>(resid + m * Ndim + n);
        float4 o4;
        o4.x = acc[mf][nf][0] + bb[nf].x + rr4.x;
        o4.y = acc[mf][nf][1] + bb[nf].y + rr4.y;
        o4.z = acc[mf][nf][2] + bb[nf].z + rr4.z;
        o4.w = acc[mf][nf][3] + bb[nf].w + rr4.w;
        *reinterpret_cast<float4*>((float*)Cout + m * Ndim + n) = o4;
      }
    }
  }
}

// ---------------- attention over T=16, one wave per (b,h,w,head) ----------------
// qkv row layout per head n: f = n*192 + [0:64)=q [64:128)=k [128:192)=v
// output o (16x64) overwrites the v-slots (already staged to LDS before write).
__global__ __launch_bounds__(64) void attn_kernel(u16* __restrict__ qkv){
  __shared__ __align__(16) u16 sq[16][72];
  __shared__ __align__(16) u16 sk[16][72];
  __shared__ __align__(16) u16 sv[16][72];
  __shared__ float sp[16][17];
  const int lane = threadIdx.x;
  int bid = blockIdx.x;
  const int n = bid % 12; bid /= 12;
  const int w = bid % 32; bid /= 32;
  const int h = bid % 32; const int b = bid / 32;
  u16* base = qkv + ((size_t)(b*16384 + h*32 + w)) * F3 + n * 192;
  const size_t tstride = (size_t)1024 * F3;   // t-step = 1024 rows

  #pragma unroll
  for (int i = 0; i < 6; i++){
    const int e8 = lane + i*64;
    const int t = e8 / 24, ck = e8 % 24;
    uint4 val = *reinterpret_cast<const uint4*>(base + (size_t)t*tstride + ck*8);
    u16* dst = (ck < 8) ? &sq[t][ck*8] : (ck < 16) ? &sk[t][(ck-8)*8] : &sv[t][(ck-16)*8];
    *reinterpret_cast<uint4*>(dst) = val;
  }
  __syncthreads();

  const int g = lane >> 4, sj = lane & 15;
  float accv[4] = {0.f, 0.f, 0.f, 0.f};
  #pragma unroll
  for (int dc = 0; dc < 8; dc++){
    union { uint4 u; u16 s[8]; } kc;
    kc.u = *reinterpret_cast<const uint4*>(&sk[sj][dc*8]);
    #pragma unroll
    for (int i = 0; i < 4; i++){
      union { uint4 u; u16 s[8]; } qc;
      qc.u = *reinterpret_cast<const uint4*>(&sq[g + i*4][dc*8]);
      #pragma unroll
      for (int e = 0; e < 8; e++)
        accv[i] += bfu2f(qc.s[e]) * bfu2f(kc.s[e]);
    }
  }
  #pragma unroll
  for (int i = 0; i < 4; i++){
    float sc = accv[i] * 0.125f;
    float mx = sc;
    #pragma unroll
    for (int o = 1; o < 16; o <<= 1) mx = fmaxf(mx, __shfl_xor(mx, o, 16));
    float p = __expf(sc - mx);
    float sm = p;
    #pragma unroll
    for (int o = 1; o < 16; o <<= 1) sm += __shfl_xor(sm, o, 16);
    sp[g + i*4][sj] = p / sm;
  }
  __syncthreads();

  #pragma unroll
  for (int t = 0; t < 16; t++){
    float o = 0.f;
    #pragma unroll
    for (int s = 0; s < 16; s++) o += sp[t][s] * bfu2f(sv[s][lane]);
    base[(size_t)t*tstride + 128 + lane] = f2bfu(o);
  }
}

// ---------------- LN2: reads attention output from v-slots of qkv ----------------
__global__ __launch_bounds__(256) void ln2_kernel(const u16* __restrict__ qkv,
    const float* __restrict__ w, const float* __restrict__ b, u16* __restrict__ y2){
  const int lane = threadIdx.x & 63, wid = threadIdx.x >> 6;
  const size_t row = (size_t)blockIdx.x * 4 + wid;
  const u16* src = qkv + row * F3 + 128;
  float v[12];
  #pragma unroll
  for (int j = 0; j < 12; j++) v[j] = bfu2f(src[j*192 + lane]);   // c = j*64+lane
  float s = 0.f, ss = 0.f;
  #pragma unroll
  for (int j = 0; j < 12; j++){ s += v[j]; ss += v[j]*v[j]; }
  #pragma unroll
  for (int o = 32; o; o >>= 1){ s += __shfl_xor(s, o, 64); ss += __shfl_xor(ss, o, 64); }
  const float mu = s * (1.f/768.f);
  const float rs = rsqrtf(ss*(1.f/768.f) - mu*mu + LNEPS);
  #pragma unroll
  for (int j = 0; j < 12; j++){
    const int c = j*64 + lane;
    y2[row * C + c] = f2bfu((v[j]-mu)*rs*w[c] + b[c]);
  }
}

extern "C" void kernel_launch(void* const* d_in, const int* in_sizes, int n_in,
                              void* d_out, int out_size, void* d_ws, size_t ws_size,
                              hipStream_t stream){
  const float* x    = (const float*)d_in[0];
  const float* ln1w = (const float*)d_in[1];
  const float* ln1b = (const float*)d_in[2];
  const float* Wqkv = (const float*)d_in[3];
  const float* bqkv = (const float*)d_in[4];
  const float* ln2w = (const float*)d_in[5];
  const float* ln2b = (const float*)d_in[6];
  const float* Wout = (const float*)d_in[7];
  const float* bout = (const float*)d_in[8];
  float* out = (float*)d_out;

  char* ws = (char*)d_ws;
  u16* qkv = (u16*)ws;                       // 32768*2304*2 = 150,994,944 B
  u16* y   = (u16*)(ws + 150994944);         // 32768*768*2  =  50,331,648 B (y1, then y2)
  u16* wq  = (u16*)(ws + 201326592);         // 2304*768*2   =   3,538,944 B
  u16* wo  = (u16*)(ws + 204865536);         // 768*768*2    =   1,179,648 B  (total 206,045,184)

  cvt_bf16<<<(F3*C + 255)/256, 256, 0, stream>>>(Wqkv, wq, F3*C);
  cvt_bf16<<<(C*C + 255)/256, 256, 0, stream>>>(Wout, wo, C*C);
  ln1_kernel<<<MROWS/4, 256, 0, stream>>>(x, ln1w, ln1b, y);
  gemm_bt<0><<<(MROWS/256)*(F3/256), 512, 0, stream>>>(y, wq, bqkv, nullptr, qkv, F3, C);
  attn_kernel<<<2*32*32*12, 64, 0, stream>>>(qkv);
  ln2_kernel<<<MROWS/4, 256, 0, stream>>>(qkv, ln2w, ln2b, y);
  gemm_bt<1><<<(MROWS/256)*(C/256), 512, 0, stream>>>(y, wo, bout, x, out, C, C);
}

// Round 10
// 356.676 us; speedup vs baseline: 1.0958x; 1.0958x over previous
//
#include <hip/hip_runtime.h>

typedef unsigned short u16;
typedef __attribute__((ext_vector_type(8))) short frag8;
typedef __attribute__((ext_vector_type(4))) float f32x4;

static constexpr int C = 768;
static constexpr int F3 = 2304;      // 3*C
static constexpr int MROWS = 32768;  // B*T*H*W
static constexpr float LNEPS = 1e-5f;

__device__ __forceinline__ float bfu2f(u16 u){
  union { unsigned u; float f; } x; x.u = (unsigned)u << 16; return x.f;
}
__device__ __forceinline__ u16 f2bfu(float f){
  union { float f; unsigned u; } x; x.f = f;
  unsigned r = x.u + 0x7fffu + ((x.u >> 16) & 1u);   // RNE bf16
  return (u16)(r >> 16);
}

__device__ __forceinline__ void gload16(const void* g, void* l){
  __builtin_amdgcn_global_load_lds(
      (const __attribute__((address_space(1))) void*)g,
      (__attribute__((address_space(3))) void*)l, 16, 0, 0);
}

// ---------------- fp32 -> bf16 weight conversion ----------------
__global__ __launch_bounds__(256) void cvt_bf16(const float* __restrict__ src,
                                                u16* __restrict__ dst, int n){
  int i = blockIdx.x * 256 + threadIdx.x;
  if (i < n) dst[i] = f2bfu(src[i]);
}

// ---------------- LN1: fp32 x -> bf16 y ----------------
__global__ __launch_bounds__(256) void ln1_kernel(const float* __restrict__ x,
    const float* __restrict__ w, const float* __restrict__ b, u16* __restrict__ y){
  const int lane = threadIdx.x & 63, wid = threadIdx.x >> 6;
  const size_t row = (size_t)blockIdx.x * 4 + wid;
  const float4* xr = reinterpret_cast<const float4*>(x + row * C);
  float v[12];
  #pragma unroll
  for (int j = 0; j < 3; j++){
    float4 t = xr[lane + j*64];
    v[j*4+0]=t.x; v[j*4+1]=t.y; v[j*4+2]=t.z; v[j*4+3]=t.w;
  }
  float s = 0.f, ss = 0.f;
  #pragma unroll
  for (int j = 0; j < 12; j++){ s += v[j]; ss += v[j]*v[j]; }
  #pragma unroll
  for (int o = 32; o; o >>= 1){ s += __shfl_xor(s, o, 64); ss += __shfl_xor(ss, o, 64); }
  const float mu = s * (1.f/768.f);
  const float rs = rsqrtf(ss*(1.f/768.f) - mu*mu + LNEPS);
  ushort4* yr = reinterpret_cast<ushort4*>(y + row * C);
  const float4* wv = reinterpret_cast<const float4*>(w);
  const float4* bv = reinterpret_cast<const float4*>(b);
  #pragma unroll
  for (int j = 0; j < 3; j++){
    float4 wj = wv[lane + j*64], bj = bv[lane + j*64];
    ushort4 o4;
    o4.x = f2bfu((v[j*4+0]-mu)*rs*wj.x + bj.x);
    o4.y = f2bfu((v[j*4+1]-mu)*rs*wj.y + bj.y);
    o4.z = f2bfu((v[j*4+2]-mu)*rs*wj.z + bj.z);
    o4.w = f2bfu((v[j*4+3]-mu)*rs*wj.w + bj.w);
    yr[lane + j*64] = o4;
  }
}

// ---------------- GEMM (R7-exact, proven 164us): C[m,n]=sum_k A[m,k]*B[n,k] ----------------
// BM=BN=256, BK=32, 24 K-tiles, 48 phases (2/K-tile: q0=mf0-3, q1=mf4-7; 16 MFMA each).
// LDS ring-4 x 32KB (A 16KB + B 16KB per K-tile) = 128KB. One half (A or B of a
// future tile, 2 gload_lds/thread) staged per phase: q0 stages B(t+2), q1 stages
// A(t+3) (stage lead 5 phases). Counted vmcnt(6) + lgkm(0) BEFORE each barrier.
// Subtile = 16r x 32k sigma-swizzled: coalesced 64B global segments per lane-quad
// AND conflict-free-per-8-lane ds_read_b128.
// MFMA operands swapped: acc quad = 4 consecutive n -> vectorized direct stores.
template<int MODE>
__global__ __launch_bounds__(512, 2) void gemm_bt(
    const u16* __restrict__ A, const u16* __restrict__ Bw,
    const float* __restrict__ bias, const float* __restrict__ resid,
    void* __restrict__ Cout, int Ndim, int K)
{
  __shared__ __align__(16) char lds[131072];
  const int tid = threadIdx.x;
  const int lane = tid & 63, wid = tid >> 6;
  const int wm = wid >> 2, wn = wid & 3;        // 2 x 4 wave grid
  const int ntn = Ndim >> 8;
  const int cpx = (int)gridDim.x >> 3;          // bijective XCD swizzle (grid%8==0)
  const int wg = ((int)blockIdx.x & 7) * cpx + ((int)blockIdx.x >> 3);
  const int bm = wg / ntn, bn = wg % ntn;
  const int m0 = bm << 8, n0 = bn << 8;

  // staging source decode (sigma^-1): lane -> (row rr, kchunk qq) of a subtile
  const int rp = lane >> 2;
  const int rr = rp ^ ((rp >> 2) & 1);
  const int qq = (lane & 3) ^ (rr & 3);
  const u16* aS = A  + (size_t)(m0 + wid*16 + rr) * K + qq*8;
  const u16* bS = Bw + (size_t)(n0 + wid*16 + rr) * K + qq*8;
  const size_t half128 = 128 * (size_t)K;

  // fragment read offset within subtile (sigma of (fr,kq)), bytes
  const int fr = lane & 15, kq = lane >> 4;
  const int sig16 = (((fr ^ ((fr >> 2) & 1)) << 2) | (kq ^ (fr & 3))) * 16;

  f32x4 acc[8][4] = {};   // [mf][nf], wave tile 128x64

  auto stA = [&](int ts){
    char* lb = lds + (ts & 3)*32768;
    gload16(aS + ts*32,           lb + wid*1024);
    gload16(aS + ts*32 + half128, lb + (8+wid)*1024);
  };
  auto stB = [&](int ts){
    char* lb = lds + (ts & 3)*32768 + 16384;
    gload16(bS + ts*32,           lb + wid*1024);
    gload16(bS + ts*32 + half128, lb + (8+wid)*1024);
  };

  // prologue: halves A0,B0,A1,B1,A2 (10 loads); vmcnt(6) retires A0,B0
  stA(0); stB(0); stA(1); stB(1); stA(2);
  asm volatile("s_waitcnt vmcnt(6)" ::: "memory");
  __builtin_amdgcn_s_barrier();

  for (int t = 0; t < 24; ++t){
    const char* base = lds + (t & 3)*32768;
    int tb = t + 2; if (tb >= 24) tb -= 24;
    int ta = t + 3; if (ta >= 24) ta -= 24;
    frag8 af[4], bf[4], ag[4];

    // ---------- phase q0: read A mf0-3 + B nf0-3, stage B(t+2) ----------
    #pragma unroll
    for (int mf = 0; mf < 4; mf++)
      af[mf] = *reinterpret_cast<const frag8*>(base + (wm*8+mf)*1024 + sig16);
    #pragma unroll
    for (int nf = 0; nf < 4; nf++)
      bf[nf] = *reinterpret_cast<const frag8*>(base + 16384 + (wn*4+nf)*1024 + sig16);
    stB(tb);
    asm volatile("s_waitcnt vmcnt(6)" ::: "memory");
    asm volatile("s_waitcnt lgkmcnt(0)" ::: "memory");
    __builtin_amdgcn_sched_barrier(0);
    __builtin_amdgcn_s_barrier();
    __builtin_amdgcn_s_setprio(1);
    #pragma unroll
    for (int mf = 0; mf < 4; mf++)
      #pragma unroll
      for (int nf = 0; nf < 4; nf++)
        acc[mf][nf] = __builtin_amdgcn_mfma_f32_16x16x32_bf16(bf[nf], af[mf], acc[mf][nf], 0, 0, 0);
    __builtin_amdgcn_s_setprio(0);

    // ---------- phase q1: read A mf4-7, stage A(t+3) ----------
    #pragma unroll
    for (int mf = 0; mf < 4; mf++)
      ag[mf] = *reinterpret_cast<const frag8*>(base + (wm*8+4+mf)*1024 + sig16);
    stA(ta);
    asm volatile("s_waitcnt vmcnt(6)" ::: "memory");
    asm volatile("s_waitcnt lgkmcnt(0)" ::: "memory");
    __builtin_amdgcn_sched_barrier(0);
    __builtin_amdgcn_s_barrier();
    __builtin_amdgcn_s_setprio(1);
    #pragma unroll
    for (int mf = 0; mf < 4; mf++)
      #pragma unroll
      for (int nf = 0; nf < 4; nf++)
        acc[4+mf][nf] = __builtin_amdgcn_mfma_f32_16x16x32_bf16(bf[nf], ag[mf], acc[4+mf][nf], 0, 0, 0);
    __builtin_amdgcn_s_setprio(0);
  }
  asm volatile("s_waitcnt vmcnt(0)" ::: "memory");   // drain wrapped tail stages

  // epilogue (swapped layout): m = lane&15 (+16mf+128wm), n-quad = (lane>>4)*4 (+16nf+64wn)
  const int em = fr, en = kq * 4;
  float4 bb[4];
  #pragma unroll
  for (int nf = 0; nf < 4; nf++)
    bb[nf] = *reinterpret_cast<const float4*>(bias + n0 + wn*64 + nf*16 + en);

  #pragma unroll
  for (int mf = 0; mf < 8; mf++){
    const size_t m = (size_t)(m0 + wm*128 + mf*16 + em);
    #pragma unroll
    for (int nf = 0; nf < 4; nf++){
      const int n = n0 + wn*64 + nf*16 + en;
      if (MODE == 0){
        ushort4 o4;
        o4.x = f2bfu(acc[mf][nf][0] + bb[nf].x);
        o4.y = f2bfu(acc[mf][nf][1] + bb[nf].y);
        o4.z = f2bfu(acc[mf][nf][2] + bb[nf].z);
        o4.w = f2bfu(acc[mf][nf][3] + bb[nf].w);
        *reinterpret_cast<ushort4*>((u16*)Cout + m * Ndim + n) = o4;
      } else {
        const float4 rr4 = *reinterpret_cast<const float4*>(resid + m * Ndim + n);
        float4 o4;
        o4.x = acc[mf][nf][0] + bb[nf].x + rr4.x;
        o4.y = acc[mf][nf][1] + bb[nf].y + rr4.y;
        o4.z = acc[mf][nf][2] + bb[nf].z + rr4.z;
        o4.w = acc[mf][nf][3] + bb[nf].w + rr4.w;
        *reinterpret_cast<float4*>((float*)Cout + m * Ndim + n) = o4;
      }
    }
  }
}

// ---------------- fused attention + LN2: one block per (b,h,w) ----------------
// 256 threads / 4 waves. Stage all 16 t-rows x 2304 into LDS (coalesced uint4,
// +8 u16 row pad -> row stride 4624B = 4-bank shift). Wave wid computes heads
// 3*wid..3*wid+2 (scores, softmax, PV; o buffered in regs then written into the
// head's v-slot columns). Barrier. LN over c=768 reading o-slots from LDS,
// coalesced y2 global writes.
__global__ __launch_bounds__(256) void attn_ln2(const u16* __restrict__ qkv,
    const float* __restrict__ w2, const float* __restrict__ b2, u16* __restrict__ y2){
  __shared__ __align__(16) u16 S[16][2312];   // 2304 + 8 pad; 73,984 B
  __shared__ float SP[4][16][17];
  const int tid = threadIdx.x;
  const int lane = tid & 63, wid = tid >> 6;
  const int bid = blockIdx.x;
  const int w = bid & 31, h = (bid >> 5) & 31, b = bid >> 10;
  const size_t rbase = (size_t)b*16384 + h*32 + w;     // + t*1024

  // ---- stage: 4608 16B-chunks, 18 per thread, coalesced ----
  #pragma unroll
  for (int it = 0; it < 18; it++){
    const int e = tid + it*256;
    const int t = e / 288, c = e % 288;
    const uint4 v = *reinterpret_cast<const uint4*>(qkv + (rbase + (size_t)t*1024)*F3 + c*8);
    *reinterpret_cast<uint4*>(&S[t][c*8]) = v;
  }
  __syncthreads();

  const int g = lane >> 4, sj = lane & 15;
  #pragma unroll
  for (int hh = 0; hh < 3; hh++){
    const int n = wid*3 + hh;
    const int q0 = n*192, k0 = q0 + 64, v0 = q0 + 128;
    // scores: lane owns rows t = g+4i, col s = sj
    float accv[4] = {0.f, 0.f, 0.f, 0.f};
    #pragma unroll
    for (int dc = 0; dc < 8; dc++){
      union { uint4 u; u16 s[8]; } kc;
      kc.u = *reinterpret_cast<const uint4*>(&S[sj][k0 + dc*8]);
      #pragma unroll
      for (int i = 0; i < 4; i++){
        union { uint4 u; u16 s[8]; } qc;
        qc.u = *reinterpret_cast<const uint4*>(&S[g + 4*i][q0 + dc*8]);
        #pragma unroll
        for (int e = 0; e < 8; e++)
          accv[i] += bfu2f(qc.s[e]) * bfu2f(kc.s[e]);
      }
    }
    #pragma unroll
    for (int i = 0; i < 4; i++){
      float sc = accv[i] * 0.125f;
      float mx = sc;
      #pragma unroll
      for (int o = 1; o < 16; o <<= 1) mx = fmaxf(mx, __shfl_xor(mx, o, 16));
      float p = __expf(sc - mx);
      float sm = p;
      #pragma unroll
      for (int o = 1; o < 16; o <<= 1) sm += __shfl_xor(sm, o, 16);
      SP[wid][g + 4*i][sj] = p / sm;
    }
    // PV: lane owns d = lane; buffer o in regs (v must stay intact), then write
    float ot[16];
    #pragma unroll
    for (int t = 0; t < 16; t++){
      float o = 0.f;
      #pragma unroll
      for (int s = 0; s < 16; s++) o += SP[wid][t][s] * bfu2f(S[s][v0 + lane]);
      ot[t] = o;
    }
    #pragma unroll
    for (int t = 0; t < 16; t++) S[t][v0 + lane] = f2bfu(ot[t]);
  }
  __syncthreads();

  // ---- LN2 over the o-slots; each wave handles 4 rows ----
  #pragma unroll
  for (int rq = 0; rq < 4; rq++){
    const int t = wid*4 + rq;
    float v[12];
    #pragma unroll
    for (int j = 0; j < 12; j++) v[j] = bfu2f(S[t][j*192 + 128 + lane]);
    float s = 0.f, ss = 0.f;
    #pragma unroll
    for (int j = 0; j < 12; j++){ s += v[j]; ss += v[j]*v[j]; }
    #pragma unroll
    for (int o = 32; o; o >>= 1){ s += __shfl_xor(s, o, 64); ss += __shfl_xor(ss, o, 64); }
    const float mu = s * (1.f/768.f);
    const float rs = rsqrtf(ss*(1.f/768.f) - mu*mu + LNEPS);
    u16* yr = y2 + (rbase + (size_t)t*1024) * C;
    #pragma unroll
    for (int j = 0; j < 12; j++){
      const int c = j*64 + lane;
      yr[c] = f2bfu((v[j]-mu)*rs*w2[c] + b2[c]);
    }
  }
}

extern "C" void kernel_launch(void* const* d_in, const int* in_sizes, int n_in,
                              void* d_out, int out_size, void* d_ws, size_t ws_size,
                              hipStream_t stream){
  const float* x    = (const float*)d_in[0];
  const float* ln1w = (const float*)d_in[1];
  const float* ln1b = (const float*)d_in[2];
  const float* Wqkv = (const float*)d_in[3];
  const float* bqkv = (const float*)d_in[4];
  const float* ln2w = (const float*)d_in[5];
  const float* ln2b = (const float*)d_in[6];
  const float* Wout = (const float*)d_in[7];
  const float* bout = (const float*)d_in[8];
  float* out = (float*)d_out;

  char* ws = (char*)d_ws;
  u16* qkv = (u16*)ws;                       // 32768*2304*2 = 150,994,944 B
  u16* y   = (u16*)(ws + 150994944);         // 32768*768*2  =  50,331,648 B (y1, then y2)
  u16* wq  = (u16*)(ws + 201326592);         // 2304*768*2   =   3,538,944 B
  u16* wo  = (u16*)(ws + 204865536);         // 768*768*2    =   1,179,648 B  (total 206,045,184)

  cvt_bf16<<<(F3*C + 255)/256, 256, 0, stream>>>(Wqkv, wq, F3*C);
  cvt_bf16<<<(C*C + 255)/256, 256, 0, stream>>>(Wout, wo, C*C);
  ln1_kernel<<<MROWS/4, 256, 0, stream>>>(x, ln1w, ln1b, y);
  gemm_bt<0><<<(MROWS/256)*(F3/256), 512, 0, stream>>>(y, wq, bqkv, nullptr, qkv, F3, C);
  attn_ln2<<<2*32*32, 256, 0, stream>>>(qkv, ln2w, ln2b, y);
  gemm_bt<1><<<(MROWS/256)*(C/256), 512, 0, stream>>>(y, wo, bout, x, out, C, C);
}

// Round 11
// 345.473 us; speedup vs baseline: 1.1313x; 1.0324x over previous
//
#include <hip/hip_runtime.h>

typedef unsigned short u16;
typedef __attribute__((ext_vector_type(8))) short frag8;
typedef __attribute__((ext_vector_type(4))) float f32x4;

static constexpr int C = 768;
static constexpr int F3 = 2304;      // 3*C
static constexpr int MROWS = 32768;  // B*T*H*W
static constexpr float LNEPS = 1e-5f;

__device__ __forceinline__ float bfu2f(u16 u){
  union { unsigned u; float f; } x; x.u = (unsigned)u << 16; return x.f;
}
__device__ __forceinline__ u16 f2bfu(float f){
  union { float f; unsigned u; } x; x.f = f;
  unsigned r = x.u + 0x7fffu + ((x.u >> 16) & 1u);   // RNE bf16
  return (u16)(r >> 16);
}

__device__ __forceinline__ void gload16(const void* g, void* l){
  __builtin_amdgcn_global_load_lds(
      (const __attribute__((address_space(1))) void*)g,
      (__attribute__((address_space(3))) void*)l, 16, 0, 0);
}

// ---------------- fp32 -> bf16 weight conversion ----------------
__global__ __launch_bounds__(256) void cvt_bf16(const float* __restrict__ src,
                                                u16* __restrict__ dst, int n){
  int i = blockIdx.x * 256 + threadIdx.x;
  if (i < n) dst[i] = f2bfu(src[i]);
}

// ---------------- LN1: fp32 x -> bf16 y ----------------
__global__ __launch_bounds__(256) void ln1_kernel(const float* __restrict__ x,
    const float* __restrict__ w, const float* __restrict__ b, u16* __restrict__ y){
  const int lane = threadIdx.x & 63, wid = threadIdx.x >> 6;
  const size_t row = (size_t)blockIdx.x * 4 + wid;
  const float4* xr = reinterpret_cast<const float4*>(x + row * C);
  float v[12];
  #pragma unroll
  for (int j = 0; j < 3; j++){
    float4 t = xr[lane + j*64];
    v[j*4+0]=t.x; v[j*4+1]=t.y; v[j*4+2]=t.z; v[j*4+3]=t.w;
  }
  float s = 0.f, ss = 0.f;
  #pragma unroll
  for (int j = 0; j < 12; j++){ s += v[j]; ss += v[j]*v[j]; }
  #pragma unroll
  for (int o = 32; o; o >>= 1){ s += __shfl_xor(s, o, 64); ss += __shfl_xor(ss, o, 64); }
  const float mu = s * (1.f/768.f);
  const float rs = rsqrtf(ss*(1.f/768.f) - mu*mu + LNEPS);
  ushort4* yr = reinterpret_cast<ushort4*>(y + row * C);
  const float4* wv = reinterpret_cast<const float4*>(w);
  const float4* bv = reinterpret_cast<const float4*>(b);
  #pragma unroll
  for (int j = 0; j < 3; j++){
    float4 wj = wv[lane + j*64], bj = bv[lane + j*64];
    ushort4 o4;
    o4.x = f2bfu((v[j*4+0]-mu)*rs*wj.x + bj.x);
    o4.y = f2bfu((v[j*4+1]-mu)*rs*wj.y + bj.y);
    o4.z = f2bfu((v[j*4+2]-mu)*rs*wj.z + bj.z);
    o4.w = f2bfu((v[j*4+3]-mu)*rs*wj.w + bj.w);
    yr[lane + j*64] = o4;
  }
}

// ---------------- GEMM: C[m,n] = sum_k A[m,k]*B[n,k]  (B^T layout) ----------------
// R11: occupancy-first. BM=128, BN=256, BK=32, 24 K-tiles, 512 threads,
// 8 waves 2M x 4N, wave tile 64x64 -> acc 64 regs; __launch_bounds__(512,4)
// => 4 waves/SIMD = 2 BLOCKS/CU (R4-R10 were 1 block/CU: acc 128 + LDS 128KB
// both forced it; lockstep phases exposed every stall -> MfmaUtil pinned 30%).
// LDS dbuf-2 x 24KB (A 8KB + B 16KB) = 48KB. Per K-tile:
//   stage(t+1) [3 gloads]; vmcnt(3) (retires stage(t), counted, never 0);
//   barrier; 8 ds_read; lgkm(0); setprio(1); 16 MFMA; setprio(0); barrier.
// RAW: vmcnt(3)+barrier => stage(t) globally landed before reads of buf[t&1].
// WAR: stage(t+1) writes buf[(t+1)&1], last read at t-1; those reads drained
// by t-1's lgkm(0) before t-1's end barrier; stage issued after it. Wrapped
// tail (t=23 -> stage 0) keeps vmcnt uniform; parity matches.
// Subtile = 16r x 32k sigma-swizzled: coalesced 64B global segments per
// lane-quad AND conflict-free-per-8-lane ds_read_b128.
// MFMA operands swapped: acc quad = 4 consecutive n -> vectorized stores.
// MODE 0: out = bf16(acc + bias); MODE 1: out = fp32(acc + bias + resid).
template<int MODE>
__global__ __launch_bounds__(512, 4) void gemm_bt(
    const u16* __restrict__ A, const u16* __restrict__ Bw,
    const float* __restrict__ bias, const float* __restrict__ resid,
    void* __restrict__ Cout, int Ndim, int K)
{
  __shared__ __align__(16) char lds[49152];     // dbuf-2 x 24KB
  const int tid = threadIdx.x;
  const int lane = tid & 63, wid = tid >> 6;
  const int wm = wid >> 2, wn = wid & 3;        // 2 x 4 wave grid, wave tile 64x64
  const int ntn = Ndim >> 8;
  const int cpx = (int)gridDim.x >> 3;          // bijective XCD swizzle (grid%8==0)
  const int wg = ((int)blockIdx.x & 7) * cpx + ((int)blockIdx.x >> 3);
  const int bm = wg / ntn, bn = wg % ntn;
  const int m0 = bm << 7, n0 = bn << 8;

  // staging source decode (sigma^-1): lane -> (row rr, kchunk qq) of a subtile
  const int rp = lane >> 2;
  const int rr = rp ^ ((rp >> 2) & 1);
  const int qq = (lane & 3) ^ (rr & 3);
  const u16* aS = A  + (size_t)(m0 + wid*16 + rr) * K + qq*8;   // A subtile rg=wid (8 total)
  const u16* bS = Bw + (size_t)(n0 + wid*16 + rr) * K + qq*8;   // B subtiles rg=wid, wid+8
  const size_t half128 = 128 * (size_t)K;

  // fragment read offset within subtile (sigma of (fr,kq)), bytes
  const int fr = lane & 15, kq = lane >> 4;
  const int sig16 = (((fr ^ ((fr >> 2) & 1)) << 2) | (kq ^ (fr & 3))) * 16;

  f32x4 acc[4][4] = {};   // [mf][nf], wave tile 64x64

  // stage K-tile ts into buf ts&1: A 8KB (1 gload) + B 16KB (2 gloads)
  auto stage = [&](int ts){
    char* lb = lds + (ts & 1)*24576;
    gload16(aS + ts*32,           lb + wid*1024);            // A rg=wid
    gload16(bS + ts*32,           lb + 8192 + wid*1024);     // B rg=wid
    gload16(bS + ts*32 + half128, lb + 8192 + (8+wid)*1024); // B rg=wid+8
  };

  stage(0);                                   // 3 loads in flight

  for (int t = 0; t < 24; ++t){
    int tn = t + 1; if (tn >= 24) tn = 0;     // wrapped tail keeps vmcnt uniform
    stage(tn);                                 // 6 outstanding
    asm volatile("s_waitcnt vmcnt(3)" ::: "memory");   // stage(t) retired (own)
    __builtin_amdgcn_s_barrier();                      // -> globally landed

    const char* base = lds + (t & 1)*24576;
    const char* pa = base + (wm*4)*1024 + sig16;          // A rg = wm*4+mf
    const char* pb = base + 8192 + (wn*4)*1024 + sig16;   // B rg = wn*4+nf
    frag8 af[4], bf[4];
    #pragma unroll
    for (int mf = 0; mf < 4; mf++) af[mf] = *reinterpret_cast<const frag8*>(pa + mf*1024);
    #pragma unroll
    for (int nf = 0; nf < 4; nf++) bf[nf] = *reinterpret_cast<const frag8*>(pb + nf*1024);
    asm volatile("s_waitcnt lgkmcnt(0)" ::: "memory");
    __builtin_amdgcn_sched_barrier(0);
    __builtin_amdgcn_s_setprio(1);
    #pragma unroll
    for (int mf = 0; mf < 4; mf++)
      #pragma unroll
      for (int nf = 0; nf < 4; nf++)
        acc[mf][nf] = __builtin_amdgcn_mfma_f32_16x16x32_bf16(bf[nf], af[mf], acc[mf][nf], 0, 0, 0);
    __builtin_amdgcn_s_setprio(0);
    __builtin_amdgcn_s_barrier();             // reads done before next stage's writes
  }
  asm volatile("s_waitcnt vmcnt(0)" ::: "memory");   // drain wrapped tail stage

  // epilogue (swapped layout): m = lane&15 (+16mf+64wm), n-quad = (lane>>4)*4 (+16nf+64wn)
  const int em = fr, en = kq * 4;
  float4 bb[4];
  #pragma unroll
  for (int nf = 0; nf < 4; nf++)
    bb[nf] = *reinterpret_cast<const float4*>(bias + n0 + wn*64 + nf*16 + en);

  #pragma unroll
  for (int mf = 0; mf < 4; mf++){
    const size_t m = (size_t)(m0 + wm*64 + mf*16 + em);
    #pragma unroll
    for (int nf = 0; nf < 4; nf++){
      const int n = n0 + wn*64 + nf*16 + en;
      if (MODE == 0){
        ushort4 o4;
        o4.x = f2bfu(acc[mf][nf][0] + bb[nf].x);
        o4.y = f2bfu(acc[mf][nf][1] + bb[nf].y);
        o4.z = f2bfu(acc[mf][nf][2] + bb[nf].z);
        o4.w = f2bfu(acc[mf][nf][3] + bb[nf].w);
        *reinterpret_cast<ushort4*>((u16*)Cout + m * Ndim + n) = o4;
      } else {
        const float4 rr4 = *reinterpret_cast<const float4*>(resid + m * Ndim + n);
        float4 o4;
        o4.x = acc[mf][nf][0] + bb[nf].x + rr4.x;
        o4.y = acc[mf][nf][1] + bb[nf].y + rr4.y;
        o4.z = acc[mf][nf][2] + bb[nf].z + rr4.z;
        o4.w = acc[mf][nf][3] + bb[nf].w + rr4.w;
        *reinterpret_cast<float4*>((float*)Cout + m * Ndim + n) = o4;
      }
    }
  }
}

// ---------------- fused attention + LN2: one block per (b,h,w) ----------------
// 256 threads / 4 waves. Stage all 16 t-rows x 2304 into LDS (coalesced uint4,
// +8 u16 row pad). Wave wid computes heads 3*wid..3*wid+2 (scores, softmax, PV;
// o buffered in regs then written into the head's v-slot columns). Barrier.
// LN over c=768 reading o-slots from LDS, coalesced y2 global writes.
__global__ __launch_bounds__(256) void attn_ln2(const u16* __restrict__ qkv,
    const float* __restrict__ w2, const float* __restrict__ b2, u16* __restrict__ y2){
  __shared__ __align__(16) u16 S[16][2312];   // 2304 + 8 pad; 73,984 B
  __shared__ float SP[4][16][17];
  const int tid = threadIdx.x;
  const int lane = tid & 63, wid = tid >> 6;
  const int bid = blockIdx.x;
  const int w = bid & 31, h = (bid >> 5) & 31, b = bid >> 10;
  const size_t rbase = (size_t)b*16384 + h*32 + w;     // + t*1024

  #pragma unroll
  for (int it = 0; it < 18; it++){
    const int e = tid + it*256;
    const int t = e / 288, c = e % 288;
    const uint4 v = *reinterpret_cast<const uint4*>(qkv + (rbase + (size_t)t*1024)*F3 + c*8);
    *reinterpret_cast<uint4*>(&S[t][c*8]) = v;
  }
  __syncthreads();

  const int g = lane >> 4, sj = lane & 15;
  #pragma unroll
  for (int hh = 0; hh < 3; hh++){
    const int n = wid*3 + hh;
    const int q0 = n*192, k0 = q0 + 64, v0 = q0 + 128;
    float accv[4] = {0.f, 0.f, 0.f, 0.f};
    #pragma unroll
    for (int dc = 0; dc < 8; dc++){
      union { uint4 u; u16 s[8]; } kc;
      kc.u = *reinterpret_cast<const uint4*>(&S[sj][k0 + dc*8]);
      #pragma unroll
      for (int i = 0; i < 4; i++){
        union { uint4 u; u16 s[8]; } qc;
        qc.u = *reinterpret_cast<const uint4*>(&S[g + 4*i][q0 + dc*8]);
        #pragma unroll
        for (int e = 0; e < 8; e++)
          accv[i] += bfu2f(qc.s[e]) * bfu2f(kc.s[e]);
      }
    }
    #pragma unroll
    for (int i = 0; i < 4; i++){
      float sc = accv[i] * 0.125f;
      float mx = sc;
      #pragma unroll
      for (int o = 1; o < 16; o <<= 1) mx = fmaxf(mx, __shfl_xor(mx, o, 16));
      float p = __expf(sc - mx);
      float sm = p;
      #pragma unroll
      for (int o = 1; o < 16; o <<= 1) sm += __shfl_xor(sm, o, 16);
      SP[wid][g + 4*i][sj] = p / sm;
    }
    float ot[16];
    #pragma unroll
    for (int t = 0; t < 16; t++){
      float o = 0.f;
      #pragma unroll
      for (int s = 0; s < 16; s++) o += SP[wid][t][s] * bfu2f(S[s][v0 + lane]);
      ot[t] = o;
    }
    #pragma unroll
    for (int t = 0; t < 16; t++) S[t][v0 + lane] = f2bfu(ot[t]);
  }
  __syncthreads();

  #pragma unroll
  for (int rq = 0; rq < 4; rq++){
    const int t = wid*4 + rq;
    float v[12];
    #pragma unroll
    for (int j = 0; j < 12; j++) v[j] = bfu2f(S[t][j*192 + 128 + lane]);
    float s = 0.f, ss = 0.f;
    #pragma unroll
    for (int j = 0; j < 12; j++){ s += v[j]; ss += v[j]*v[j]; }
    #pragma unroll
    for (int o = 32; o; o >>= 1){ s += __shfl_xor(s, o, 64); ss += __shfl_xor(ss, o, 64); }
    const float mu = s * (1.f/768.f);
    const float rs = rsqrtf(ss*(1.f/768.f) - mu*mu + LNEPS);
    u16* yr = y2 + (rbase + (size_t)t*1024) * C;
    #pragma unroll
    for (int j = 0; j < 12; j++){
      const int c = j*64 + lane;
      yr[c] = f2bfu((v[j]-mu)*rs*w2[c] + b2[c]);
    }
  }
}

extern "C" void kernel_launch(void* const* d_in, const int* in_sizes, int n_in,
                              void* d_out, int out_size, void* d_ws, size_t ws_size,
                              hipStream_t stream){
  const float* x    = (const float*)d_in[0];
  const float* ln1w = (const float*)d_in[1];
  const float* ln1b = (const float*)d_in[2];
  const float* Wqkv = (const float*)d_in[3];
  const float* bqkv = (const float*)d_in[4];
  const float* ln2w = (const float*)d_in[5];
  const float* ln2b = (const float*)d_in[6];
  const float* Wout = (const float*)d_in[7];
  const float* bout = (const float*)d_in[8];
  float* out = (float*)d_out;

  char* ws = (char*)d_ws;
  u16* qkv = (u16*)ws;                       // 32768*2304*2 = 150,994,944 B
  u16* y   = (u16*)(ws + 150994944);         // 32768*768*2  =  50,331,648 B (y1, then y2)
  u16* wq  = (u16*)(ws + 201326592);         // 2304*768*2   =   3,538,944 B
  u16* wo  = (u16*)(ws + 204865536);         // 768*768*2    =   1,179,648 B  (total 206,045,184)

  cvt_bf16<<<(F3*C + 255)/256, 256, 0, stream>>>(Wqkv, wq, F3*C);
  cvt_bf16<<<(C*C + 255)/256, 256, 0, stream>>>(Wout, wo, C*C);
  ln1_kernel<<<MROWS/4, 256, 0, stream>>>(x, ln1w, ln1b, y);
  gemm_bt<0><<<(MROWS/128)*(F3/256), 512, 0, stream>>>(y, wq, bqkv, nullptr, qkv, F3, C);
  attn_ln2<<<2*32*32, 256, 0, stream>>>(qkv, ln2w, ln2b, y);
  gemm_bt<1><<<(MROWS/128)*(C/256), 512, 0, stream>>>(y, wo, bout, x, out, C, C);
}

// Round 12
// 337.114 us; speedup vs baseline: 1.1594x; 1.0248x over previous
//
#include <hip/hip_runtime.h>

typedef unsigned short u16;
typedef __attribute__((ext_vector_type(8))) short frag8;
typedef __attribute__((ext_vector_type(4))) float f32x4;

static constexpr int C = 768;
static constexpr int F3 = 2304;      // 3*C
static constexpr int MROWS = 32768;  // B*T*H*W
static constexpr float LNEPS = 1e-5f;

__device__ __forceinline__ float bfu2f(u16 u){
  union { unsigned u; float f; } x; x.u = (unsigned)u << 16; return x.f;
}
__device__ __forceinline__ u16 f2bfu(float f){
  union { float f; unsigned u; } x; x.f = f;
  unsigned r = x.u + 0x7fffu + ((x.u >> 16) & 1u);   // RNE bf16
  return (u16)(r >> 16);
}

__device__ __forceinline__ void gload16(const void* g, void* l){
  __builtin_amdgcn_global_load_lds(
      (const __attribute__((address_space(1))) void*)g,
      (__attribute__((address_space(3))) void*)l, 16, 0, 0);
}

// ---------------- fp32 -> bf16 weight conversion ----------------
__global__ __launch_bounds__(256) void cvt_bf16(const float* __restrict__ src,
                                                u16* __restrict__ dst, int n){
  int i = blockIdx.x * 256 + threadIdx.x;
  if (i < n) dst[i] = f2bfu(src[i]);
}

// ---------------- LN1: fp32 x -> bf16 y ----------------
__global__ __launch_bounds__(256) void ln1_kernel(const float* __restrict__ x,
    const float* __restrict__ w, const float* __restrict__ b, u16* __restrict__ y){
  const int lane = threadIdx.x & 63, wid = threadIdx.x >> 6;
  const size_t row = (size_t)blockIdx.x * 4 + wid;
  const float4* xr = reinterpret_cast<const float4*>(x + row * C);
  float v[12];
  #pragma unroll
  for (int j = 0; j < 3; j++){
    float4 t = xr[lane + j*64];
    v[j*4+0]=t.x; v[j*4+1]=t.y; v[j*4+2]=t.z; v[j*4+3]=t.w;
  }
  float s = 0.f, ss = 0.f;
  #pragma unroll
  for (int j = 0; j < 12; j++){ s += v[j]; ss += v[j]*v[j]; }
  #pragma unroll
  for (int o = 32; o; o >>= 1){ s += __shfl_xor(s, o, 64); ss += __shfl_xor(ss, o, 64); }
  const float mu = s * (1.f/768.f);
  const float rs = rsqrtf(ss*(1.f/768.f) - mu*mu + LNEPS);
  ushort4* yr = reinterpret_cast<ushort4*>(y + row * C);
  const float4* wv = reinterpret_cast<const float4*>(w);
  const float4* bv = reinterpret_cast<const float4*>(b);
  #pragma unroll
  for (int j = 0; j < 3; j++){
    float4 wj = wv[lane + j*64], bj = bv[lane + j*64];
    ushort4 o4;
    o4.x = f2bfu((v[j*4+0]-mu)*rs*wj.x + bj.x);
    o4.y = f2bfu((v[j*4+1]-mu)*rs*wj.y + bj.y);
    o4.z = f2bfu((v[j*4+2]-mu)*rs*wj.z + bj.z);
    o4.w = f2bfu((v[j*4+3]-mu)*rs*wj.w + bj.w);
    yr[lane + j*64] = o4;
  }
}

// ---------------- GEMM: C[m,n] = sum_k A[m,k]*B[n,k]  (B^T layout) ----------------
// R12: both constraints at once. BM=128, BN=256, BK=32, 24 K-tiles.
// 256 threads / 4 waves (1M x 4N), wave tile 128x64 -> acc 128 regs,
// FLOP/LDS-byte = 29.1 incl. staging (>26.4 break-even; R11's 64x64 was 23.8
// -> LDS-BW-bound regardless of occupancy). __launch_bounds__(256,2):
// ~210 VGPR/wave -> 2 waves/SIMD = 2 INDEPENDENT blocks/CU (96KB LDS total);
// independent barriers let one block's MFMA cover the other's stage stall
// (m114 overlap) - the thing R4-R10's single lockstep block couldn't do.
// Per K-tile: stage(t+1) [6 gloads/thread]; vmcnt(6) (counted, retires
// stage(t), never 0); barrier; 12 ds_read; lgkm(0); setprio(1); 32 MFMA;
// setprio(0); barrier. RAW/WAR as R11 (absmax-verified schedule), wrapped tail.
// Subtile = 16r x 32k sigma-swizzled: coalesced 64B global segments per
// lane-quad AND conflict-free-per-quarter-wave ds_read_b128.
// MFMA operands swapped: acc quad = 4 consecutive n -> vectorized stores.
// MODE 0: out = bf16(acc + bias); MODE 1: out = fp32(acc + bias + resid).
template<int MODE>
__global__ __launch_bounds__(256, 2) void gemm_bt(
    const u16* __restrict__ A, const u16* __restrict__ Bw,
    const float* __restrict__ bias, const float* __restrict__ resid,
    void* __restrict__ Cout, int Ndim, int K)
{
  __shared__ __align__(16) char lds[49152];     // dbuf-2 x (A 8KB + B 16KB)
  const int tid = threadIdx.x;
  const int lane = tid & 63, wn = tid >> 6;     // 4 waves, wave tile 128x64 at col wn*64
  const int ntn = Ndim >> 8;
  const int cpx = (int)gridDim.x >> 3;          // bijective XCD swizzle (grid%8==0)
  const int wg = ((int)blockIdx.x & 7) * cpx + ((int)blockIdx.x >> 3);
  const int bm = wg / ntn, bn = wg % ntn;
  const int m0 = bm << 7, n0 = bn << 8;

  // staging source decode (sigma^-1): lane -> (row rr, kchunk qq) of a subtile
  const int rp = lane >> 2;
  const int rr = rp ^ ((rp >> 2) & 1);
  const int qq = (lane & 3) ^ (rr & 3);
  const u16* aS = A  + (size_t)(m0 + rr) * K + qq*8;   // + rg*16*K ; A rg 0..7
  const u16* bS = Bw + (size_t)(n0 + rr) * K + qq*8;   // + rg*16*K ; B rg 0..15
  const size_t rgK = 16 * (size_t)K;

  // fragment read offset within subtile (sigma of (fr,kq)), bytes
  const int fr = lane & 15, kq = lane >> 4;
  const int sig16 = (((fr ^ ((fr >> 2) & 1)) << 2) | (kq ^ (fr & 3))) * 16;

  f32x4 acc[8][4] = {};   // [mf][nf], wave tile 128x64

  // stage K-tile ts into buf ts&1: wave wn stages A rg {2wn,2wn+1}, B rg {4wn..4wn+3}
  auto stage = [&](int ts){
    char* lb = lds + (ts & 1)*24576;
    const u16* a = aS + ts*32;
    const u16* b = bS + ts*32;
    gload16(a + (size_t)(2*wn    )*rgK, lb + (2*wn    )*1024);
    gload16(a + (size_t)(2*wn + 1)*rgK, lb + (2*wn + 1)*1024);
    #pragma unroll
    for (int i = 0; i < 4; i++)
      gload16(b + (size_t)(4*wn + i)*rgK, lb + 8192 + (4*wn + i)*1024);
  };

  stage(0);                                   // 6 loads in flight

  for (int t = 0; t < 24; ++t){
    int tn = t + 1; if (tn >= 24) tn = 0;     // wrapped tail keeps vmcnt uniform
    stage(tn);                                 // 12 outstanding
    asm volatile("s_waitcnt vmcnt(6)" ::: "memory");   // stage(t) retired (own)
    __builtin_amdgcn_s_barrier();                      // -> globally landed

    const char* base = lds + (t & 1)*24576;
    const char* pb = base + 8192 + (wn*4)*1024 + sig16;   // B rg = wn*4+nf
    frag8 af[8], bf[4];
    #pragma unroll
    for (int nf = 0; nf < 4; nf++) bf[nf] = *reinterpret_cast<const frag8*>(pb + nf*1024);
    #pragma unroll
    for (int mf = 0; mf < 8; mf++) af[mf] = *reinterpret_cast<const frag8*>(base + mf*1024 + sig16);
    asm volatile("s_waitcnt lgkmcnt(0)" ::: "memory");
    __builtin_amdgcn_sched_barrier(0);
    __builtin_amdgcn_s_setprio(1);
    #pragma unroll
    for (int mf = 0; mf < 8; mf++)
      #pragma unroll
      for (int nf = 0; nf < 4; nf++)
        acc[mf][nf] = __builtin_amdgcn_mfma_f32_16x16x32_bf16(bf[nf], af[mf], acc[mf][nf], 0, 0, 0);
    __builtin_amdgcn_s_setprio(0);
    __builtin_amdgcn_s_barrier();             // reads done before next stage's writes
  }
  asm volatile("s_waitcnt vmcnt(0)" ::: "memory");   // drain wrapped tail stage

  // epilogue (swapped layout): m = lane&15 (+16mf), n-quad = (lane>>4)*4 (+16nf+64wn)
  const int em = fr, en = kq * 4;
  float4 bb[4];
  #pragma unroll
  for (int nf = 0; nf < 4; nf++)
    bb[nf] = *reinterpret_cast<const float4*>(bias + n0 + wn*64 + nf*16 + en);

  #pragma unroll
  for (int mf = 0; mf < 8; mf++){
    const size_t m = (size_t)(m0 + mf*16 + em);
    #pragma unroll
    for (int nf = 0; nf < 4; nf++){
      const int n = n0 + wn*64 + nf*16 + en;
      if (MODE == 0){
        ushort4 o4;
        o4.x = f2bfu(acc[mf][nf][0] + bb[nf].x);
        o4.y = f2bfu(acc[mf][nf][1] + bb[nf].y);
        o4.z = f2bfu(acc[mf][nf][2] + bb[nf].z);
        o4.w = f2bfu(acc[mf][nf][3] + bb[nf].w);
        *reinterpret_cast<ushort4*>((u16*)Cout + m * Ndim + n) = o4;
      } else {
        const float4 rr4 = *reinterpret_cast<const float4*>(resid + m * Ndim + n);
        float4 o4;
        o4.x = acc[mf][nf][0] + bb[nf].x + rr4.x;
        o4.y = acc[mf][nf][1] + bb[nf].y + rr4.y;
        o4.z = acc[mf][nf][2] + bb[nf].z + rr4.z;
        o4.w = acc[mf][nf][3] + bb[nf].w + rr4.w;
        *reinterpret_cast<float4*>((float*)Cout + m * Ndim + n) = o4;
      }
    }
  }
}

// ---------------- fused attention + LN2: one block per (b,h,w) ----------------
// 256 threads / 4 waves. Stage all 16 t-rows x 2304 into LDS (coalesced uint4,
// +8 u16 row pad). Wave wid computes heads 3*wid..3*wid+2 (scores, softmax, PV;
// o buffered in regs then written into the head's v-slot columns). Barrier.
// LN over c=768 reading o-slots from LDS, coalesced y2 global writes.
__global__ __launch_bounds__(256) void attn_ln2(const u16* __restrict__ qkv,
    const float* __restrict__ w2, const float* __restrict__ b2, u16* __restrict__ y2){
  __shared__ __align__(16) u16 S[16][2312];   // 2304 + 8 pad; 73,984 B
  __shared__ float SP[4][16][17];
  const int tid = threadIdx.x;
  const int lane = tid & 63, wid = tid >> 6;
  const int bid = blockIdx.x;
  const int w = bid & 31, h = (bid >> 5) & 31, b = bid >> 10;
  const size_t rbase = (size_t)b*16384 + h*32 + w;     // + t*1024

  #pragma unroll
  for (int it = 0; it < 18; it++){
    const int e = tid + it*256;
    const int t = e / 288, c = e % 288;
    const uint4 v = *reinterpret_cast<const uint4*>(qkv + (rbase + (size_t)t*1024)*F3 + c*8);
    *reinterpret_cast<uint4*>(&S[t][c*8]) = v;
  }
  __syncthreads();

  const int g = lane >> 4, sj = lane & 15;
  #pragma unroll
  for (int hh = 0; hh < 3; hh++){
    const int n = wid*3 + hh;
    const int q0 = n*192, k0 = q0 + 64, v0 = q0 + 128;
    float accv[4] = {0.f, 0.f, 0.f, 0.f};
    #pragma unroll
    for (int dc = 0; dc < 8; dc++){
      union { uint4 u; u16 s[8]; } kc;
      kc.u = *reinterpret_cast<const uint4*>(&S[sj][k0 + dc*8]);
      #pragma unroll
      for (int i = 0; i < 4; i++){
        union { uint4 u; u16 s[8]; } qc;
        qc.u = *reinterpret_cast<const uint4*>(&S[g + 4*i][q0 + dc*8]);
        #pragma unroll
        for (int e = 0; e < 8; e++)
          accv[i] += bfu2f(qc.s[e]) * bfu2f(kc.s[e]);
      }
    }
    #pragma unroll
    for (int i = 0; i < 4; i++){
      float sc = accv[i] * 0.125f;
      float mx = sc;
      #pragma unroll
      for (int o = 1; o < 16; o <<= 1) mx = fmaxf(mx, __shfl_xor(mx, o, 16));
      float p = __expf(sc - mx);
      float sm = p;
      #pragma unroll
      for (int o = 1; o < 16; o <<= 1) sm += __shfl_xor(sm, o, 16);
      SP[wid][g + 4*i][sj] = p / sm;
    }
    float ot[16];
    #pragma unroll
    for (int t = 0; t < 16; t++){
      float o = 0.f;
      #pragma unroll
      for (int s = 0; s < 16; s++) o += SP[wid][t][s] * bfu2f(S[s][v0 + lane]);
      ot[t] = o;
    }
    #pragma unroll
    for (int t = 0; t < 16; t++) S[t][v0 + lane] = f2bfu(ot[t]);
  }
  __syncthreads();

  #pragma unroll
  for (int rq = 0; rq < 4; rq++){
    const int t = wid*4 + rq;
    float v[12];
    #pragma unroll
    for (int j = 0; j < 12; j++) v[j] = bfu2f(S[t][j*192 + 128 + lane]);
    float s = 0.f, ss = 0.f;
    #pragma unroll
    for (int j = 0; j < 12; j++){ s += v[j]; ss += v[j]*v[j]; }
    #pragma unroll
    for (int o = 32; o; o >>= 1){ s += __shfl_xor(s, o, 64); ss += __shfl_xor(ss, o, 64); }
    const float mu = s * (1.f/768.f);
    const float rs = rsqrtf(ss*(1.f/768.f) - mu*mu + LNEPS);
    u16* yr = y2 + (rbase + (size_t)t*1024) * C;
    #pragma unroll
    for (int j = 0; j < 12; j++){
      const int c = j*64 + lane;
      yr[c] = f2bfu((v[j]-mu)*rs*w2[c] + b2[c]);
    }
  }
}

extern "C" void kernel_launch(void* const* d_in, const int* in_sizes, int n_in,
                              void* d_out, int out_size, void* d_ws, size_t ws_size,
                              hipStream_t stream){
  const float* x    = (const float*)d_in[0];
  const float* ln1w = (const float*)d_in[1];
  const float* ln1b = (const float*)d_in[2];
  const float* Wqkv = (const float*)d_in[3];
  const float* bqkv = (const float*)d_in[4];
  const float* ln2w = (const float*)d_in[5];
  const float* ln2b = (const float*)d_in[6];
  const float* Wout = (const float*)d_in[7];
  const float* bout = (const float*)d_in[8];
  float* out = (float*)d_out;

  char* ws = (char*)d_ws;
  u16* qkv = (u16*)ws;                       // 32768*2304*2 = 150,994,944 B
  u16* y   = (u16*)(ws + 150994944);         // 32768*768*2  =  50,331,648 B (y1, then y2)
  u16* wq  = (u16*)(ws + 201326592);         // 2304*768*2   =   3,538,944 B
  u16* wo  = (u16*)(ws + 204865536);         // 768*768*2    =   1,179,648 B  (total 206,045,184)

  cvt_bf16<<<(F3*C + 255)/256, 256, 0, stream>>>(Wqkv, wq, F3*C);
  cvt_bf16<<<(C*C + 255)/256, 256, 0, stream>>>(Wout, wo, C*C);
  ln1_kernel<<<MROWS/4, 256, 0, stream>>>(x, ln1w, ln1b, y);
  gemm_bt<0><<<(MROWS/128)*(F3/256), 256, 0, stream>>>(y, wq, bqkv, nullptr, qkv, F3, C);
  attn_ln2<<<2*32*32, 256, 0, stream>>>(qkv, ln2w, ln2b, y);
  gemm_bt<1><<<(MROWS/128)*(C/256), 256, 0, stream>>>(y, wo, bout, x, out, C, C);
}

// Round 14
// 316.520 us; speedup vs baseline: 1.2348x; 1.0651x over previous
//
#include <hip/hip_runtime.h>

typedef unsigned short u16;
typedef __attribute__((ext_vector_type(8))) short frag8;
typedef __attribute__((ext_vector_type(4))) float f32x4;

static constexpr int C = 768;
static constexpr int F3 = 2304;      // 3*C
static constexpr int MROWS = 32768;  // B*T*H*W
static constexpr float LNEPS = 1e-5f;

__device__ __forceinline__ float bfu2f(u16 u){
  union { unsigned u; float f; } x; x.u = (unsigned)u << 16; return x.f;
}
__device__ __forceinline__ u16 f2bfu(float f){
  union { float f; unsigned u; } x; x.f = f;
  unsigned r = x.u + 0x7fffu + ((x.u >> 16) & 1u);   // RNE bf16
  return (u16)(r >> 16);
}

__device__ __forceinline__ void gload16(const void* g, void* l){
  __builtin_amdgcn_global_load_lds(
      (const __attribute__((address_space(1))) void*)g,
      (__attribute__((address_space(3))) void*)l, 16, 0, 0);
}

// ---------------- fp32 -> bf16 weight conversion ----------------
__global__ __launch_bounds__(256) void cvt_bf16(const float* __restrict__ src,
                                                u16* __restrict__ dst, int n){
  int i = blockIdx.x * 256 + threadIdx.x;
  if (i < n) dst[i] = f2bfu(src[i]);
}

// ---------------- LN1: fp32 x -> bf16 y ----------------
__global__ __launch_bounds__(256) void ln1_kernel(const float* __restrict__ x,
    const float* __restrict__ w, const float* __restrict__ b, u16* __restrict__ y){
  const int lane = threadIdx.x & 63, wid = threadIdx.x >> 6;
  const size_t row = (size_t)blockIdx.x * 4 + wid;
  const float4* xr = reinterpret_cast<const float4*>(x + row * C);
  float v[12];
  #pragma unroll
  for (int j = 0; j < 3; j++){
    float4 t = xr[lane + j*64];
    v[j*4+0]=t.x; v[j*4+1]=t.y; v[j*4+2]=t.z; v[j*4+3]=t.w;
  }
  float s = 0.f, ss = 0.f;
  #pragma unroll
  for (int j = 0; j < 12; j++){ s += v[j]; ss += v[j]*v[j]; }
  #pragma unroll
  for (int o = 32; o; o >>= 1){ s += __shfl_xor(s, o, 64); ss += __shfl_xor(ss, o, 64); }
  const float mu = s * (1.f/768.f);
  const float rs = rsqrtf(ss*(1.f/768.f) - mu*mu + LNEPS);
  ushort4* yr = reinterpret_cast<ushort4*>(y + row * C);
  const float4* wv = reinterpret_cast<const float4*>(w);
  const float4* bv = reinterpret_cast<const float4*>(b);
  #pragma unroll
  for (int j = 0; j < 3; j++){
    float4 wj = wv[lane + j*64], bj = bv[lane + j*64];
    ushort4 o4;
    o4.x = f2bfu((v[j*4+0]-mu)*rs*wj.x + bj.x);
    o4.y = f2bfu((v[j*4+1]-mu)*rs*wj.y + bj.y);
    o4.z = f2bfu((v[j*4+2]-mu)*rs*wj.z + bj.z);
    o4.w = f2bfu((v[j*4+3]-mu)*rs*wj.w + bj.w);
    yr[lane + j*64] = o4;
  }
}

// ---------------- GEMM (R12, unchanged): C[m,n] = sum_k A[m,k]*B[n,k] ----------------
template<int MODE>
__global__ __launch_bounds__(256, 2) void gemm_bt(
    const u16* __restrict__ A, const u16* __restrict__ Bw,
    const float* __restrict__ bias, const float* __restrict__ resid,
    void* __restrict__ Cout, int Ndim, int K)
{
  __shared__ __align__(16) char lds[49152];     // dbuf-2 x (A 8KB + B 16KB)
  const int tid = threadIdx.x;
  const int lane = tid & 63, wn = tid >> 6;     // 4 waves, wave tile 128x64 at col wn*64
  const int ntn = Ndim >> 8;
  const int cpx = (int)gridDim.x >> 3;          // bijective XCD swizzle (grid%8==0)
  const int wg = ((int)blockIdx.x & 7) * cpx + ((int)blockIdx.x >> 3);
  const int bm = wg / ntn, bn = wg % ntn;
  const int m0 = bm << 7, n0 = bn << 8;

  const int rp = lane >> 2;
  const int rr = rp ^ ((rp >> 2) & 1);
  const int qq = (lane & 3) ^ (rr & 3);
  const u16* aS = A  + (size_t)(m0 + rr) * K + qq*8;
  const u16* bS = Bw + (size_t)(n0 + rr) * K + qq*8;
  const size_t rgK = 16 * (size_t)K;

  const int fr = lane & 15, kq = lane >> 4;
  const int sig16 = (((fr ^ ((fr >> 2) & 1)) << 2) | (kq ^ (fr & 3))) * 16;

  f32x4 acc[8][4] = {};   // [mf][nf], wave tile 128x64

  auto stage = [&](int ts){
    char* lb = lds + (ts & 1)*24576;
    const u16* a = aS + ts*32;
    const u16* b = bS + ts*32;
    gload16(a + (size_t)(2*wn    )*rgK, lb + (2*wn    )*1024);
    gload16(a + (size_t)(2*wn + 1)*rgK, lb + (2*wn + 1)*1024);
    #pragma unroll
    for (int i = 0; i < 4; i++)
      gload16(b + (size_t)(4*wn + i)*rgK, lb + 8192 + (4*wn + i)*1024);
  };

  stage(0);

  for (int t = 0; t < 24; ++t){
    int tn = t + 1; if (tn >= 24) tn = 0;
    stage(tn);
    asm volatile("s_waitcnt vmcnt(6)" ::: "memory");
    __builtin_amdgcn_s_barrier();

    const char* base = lds + (t & 1)*24576;
    const char* pb = base + 8192 + (wn*4)*1024 + sig16;
    frag8 af[8], bf[4];
    #pragma unroll
    for (int nf = 0; nf < 4; nf++) bf[nf] = *reinterpret_cast<const frag8*>(pb + nf*1024);
    #pragma unroll
    for (int mf = 0; mf < 8; mf++) af[mf] = *reinterpret_cast<const frag8*>(base + mf*1024 + sig16);
    asm volatile("s_waitcnt lgkmcnt(0)" ::: "memory");
    __builtin_amdgcn_sched_barrier(0);
    __builtin_amdgcn_s_setprio(1);
    #pragma unroll
    for (int mf = 0; mf < 8; mf++)
      #pragma unroll
      for (int nf = 0; nf < 4; nf++)
        acc[mf][nf] = __builtin_amdgcn_mfma_f32_16x16x32_bf16(bf[nf], af[mf], acc[mf][nf], 0, 0, 0);
    __builtin_amdgcn_s_setprio(0);
    __builtin_amdgcn_s_barrier();
  }
  asm volatile("s_waitcnt vmcnt(0)" ::: "memory");

  const int em = fr, en = kq * 4;
  float4 bb[4];
  #pragma unroll
  for (int nf = 0; nf < 4; nf++)
    bb[nf] = *reinterpret_cast<const float4*>(bias + n0 + wn*64 + nf*16 + en);

  #pragma unroll
  for (int mf = 0; mf < 8; mf++){
    const size_t m = (size_t)(m0 + mf*16 + em);
    #pragma unroll
    for (int nf = 0; nf < 4; nf++){
      const int n = n0 + wn*64 + nf*16 + en;
      if (MODE == 0){
        ushort4 o4;
        o4.x = f2bfu(acc[mf][nf][0] + bb[nf].x);
        o4.y = f2bfu(acc[mf][nf][1] + bb[nf].y);
        o4.z = f2bfu(acc[mf][nf][2] + bb[nf].z);
        o4.w = f2bfu(acc[mf][nf][3] + bb[nf].w);
        *reinterpret_cast<ushort4*>((u16*)Cout + m * Ndim + n) = o4;
      } else {
        const float4 rr4 = *reinterpret_cast<const float4*>(resid + m * Ndim + n);
        float4 o4;
        o4.x = acc[mf][nf][0] + bb[nf].x + rr4.x;
        o4.y = acc[mf][nf][1] + bb[nf].y + rr4.y;
        o4.z = acc[mf][nf][2] + bb[nf].z + rr4.z;
        o4.w = acc[mf][nf][3] + bb[nf].w + rr4.w;
        *reinterpret_cast<float4*>((float*)Cout + m * Ndim + n) = o4;
      }
    }
  }
}

// ---------------- fused MFMA attention + LN2: one block per (b,h,w) ----------------
// R14 = R13 + Vt pad zeroing. R13's NaN: vf's kq>=2 reads hit UNINITIALIZED
// Vt pad columns (el. 16..19 mod 20 + 16-el tail); pf zeros annihilate finite
// garbage but 0 x Inf/NaN = NaN inside the MFMA. Pads are disjoint from all
// scatter-staging writes -> zero them without an extra barrier.
__global__ __launch_bounds__(256, 2) void attn_ln2(const u16* __restrict__ qkv,
    const float* __restrict__ w2, const float* __restrict__ b2, u16* __restrict__ y2){
  __shared__ __align__(16) u16 S[16][1544];   // 49,408 B
  __shared__ __align__(16) u16 Vt[15376];     // 30,752 B (12*64*20 + 16 tail)
  const int tid = threadIdx.x;
  const int lane = tid & 63, wid = tid >> 6;
  const int bid = blockIdx.x;
  const int w = bid & 31, h = (bid >> 5) & 31, b = bid >> 10;
  const size_t rbase = (size_t)b*16384 + h*32 + w;     // + t*1024

  // ---- zero Vt pad columns + tail (NaN guard; disjoint from staging writes) ----
  #pragma unroll
  for (int i = 0; i < 4; i++){
    const int idx = tid + i*256;
    if (idx < 772){
      const int off = (idx < 768) ? ((idx >> 6)*1280 + (idx & 63)*20 + 16)
                                  : (15360 + (idx - 768)*4);
      uint2 z; z.x = 0u; z.y = 0u;
      *reinterpret_cast<uint2*>(&Vt[off]) = z;
    }
  }

  // ---- stage q,k into S (coalesced 16B; 12 chunks/thread) ----
  #pragma unroll
  for (int it = 0; it < 12; it++){
    const int e = tid + it*256;
    const int t = e / 192, c = e % 192;
    const int n = c >> 4, p = c & 15;
    const uint4 v = *reinterpret_cast<const uint4*>(qkv + (rbase + (size_t)t*1024)*F3 + (n*24 + p)*8);
    *reinterpret_cast<uint4*>(&S[t][n*128 + p*8]) = v;
  }
  // ---- stage V transposed into Vt (6 chunks/thread, 8 u16 scatter each) ----
  #pragma unroll
  for (int it = 0; it < 6; it++){
    const int e = tid + it*256;
    const int t = e / 96, c = e % 96;
    const int n = c >> 3, j = c & 7;
    union { uint4 u; u16 s[8]; } vv;
    vv.u = *reinterpret_cast<const uint4*>(qkv + (rbase + (size_t)t*1024)*F3 + (n*24 + 16 + j)*8);
    #pragma unroll
    for (int x = 0; x < 8; x++)
      Vt[n*1280 + (j*8 + x)*20 + t] = vv.s[x];
  }
  __syncthreads();

  const int q = lane >> 4, tcol = lane & 15;
  unsigned pf[3][4];

  // ---- Phase A: QK^T + softmax + P-frag build, all 3 heads ----
  #pragma unroll
  for (int hh = 0; hh < 3; hh++){
    const int n = wid*3 + hh;
    const int qc = n*128, kc = n*128 + 64;
    frag8 qf0 = *reinterpret_cast<const frag8*>(&S[tcol][qc + q*8]);
    frag8 qf1 = *reinterpret_cast<const frag8*>(&S[tcol][qc + 32 + q*8]);
    frag8 kf0 = *reinterpret_cast<const frag8*>(&S[tcol][kc + q*8]);
    frag8 kf1 = *reinterpret_cast<const frag8*>(&S[tcol][kc + 32 + q*8]);
    f32x4 sa = {};
    sa = __builtin_amdgcn_mfma_f32_16x16x32_bf16(kf0, qf0, sa, 0, 0, 0);
    sa = __builtin_amdgcn_mfma_f32_16x16x32_bf16(kf1, qf1, sa, 0, 0, 0);
    const float sc0 = sa[0]*0.125f, sc1 = sa[1]*0.125f;
    const float sc2 = sa[2]*0.125f, sc3 = sa[3]*0.125f;
    float mx = fmaxf(fmaxf(sc0, sc1), fmaxf(sc2, sc3));
    mx = fmaxf(mx, __shfl_xor(mx, 16, 64));
    mx = fmaxf(mx, __shfl_xor(mx, 32, 64));
    float p0 = __expf(sc0-mx), p1 = __expf(sc1-mx), p2 = __expf(sc2-mx), p3 = __expf(sc3-mx);
    float sm = p0+p1+p2+p3;
    sm += __shfl_xor(sm, 16, 64);
    sm += __shfl_xor(sm, 32, 64);
    const float inv = 1.f / sm;
    const unsigned b0 = (unsigned)f2bfu(p0*inv) | ((unsigned)f2bfu(p1*inv) << 16);
    const unsigned b1 = (unsigned)f2bfu(p2*inv) | ((unsigned)f2bfu(p3*inv) << 16);
    // redistribute: lane(t,q) holds s=4q..4q+3; frag needs s=8q..8q+7 (q<2), 0 else
    const unsigned t0 = __shfl((unsigned)b0, (lane+16)&63, 64);
    const unsigned t1 = __shfl((unsigned)b1, (lane+16)&63, 64);
    const unsigned t2 = __shfl((unsigned)b0, (lane+32)&63, 64);
    const unsigned t3 = __shfl((unsigned)b1, (lane+32)&63, 64);
    pf[hh][0] = (q==0) ? b0 : ((q==1) ? t0 : 0u);
    pf[hh][1] = (q==0) ? b1 : ((q==1) ? t1 : 0u);
    pf[hh][2] = (q==0) ? t0 : ((q==1) ? t2 : 0u);
    pf[hh][3] = (q==0) ? t1 : ((q==1) ? t3 : 0u);
  }
  __syncthreads();

  // ---- Phase B: PV + O writes into S cols 0..767 ----
  #pragma unroll
  for (int hh = 0; hh < 3; hh++){
    const int n = wid*3 + hh;
    union { frag8 f; unsigned u[4]; } pu;
    pu.u[0] = pf[hh][0]; pu.u[1] = pf[hh][1]; pu.u[2] = pf[hh][2]; pu.u[3] = pf[hh][3];
    #pragma unroll
    for (int dcv = 0; dcv < 4; dcv++){
      union { frag8 f; uint2 v2[2]; } vf;
      const int vi = n*1280 + (dcv*16 + tcol)*20 + q*8;
      vf.v2[0] = *reinterpret_cast<const uint2*>(&Vt[vi]);
      vf.v2[1] = *reinterpret_cast<const uint2*>(&Vt[vi + 4]);
      f32x4 oa = {};
      oa = __builtin_amdgcn_mfma_f32_16x16x32_bf16(vf.f, pu.f, oa, 0, 0, 0);
      uint2 ow;
      ow.x = (unsigned)f2bfu(oa[0]) | ((unsigned)f2bfu(oa[1]) << 16);
      ow.y = (unsigned)f2bfu(oa[2]) | ((unsigned)f2bfu(oa[3]) << 16);
      *reinterpret_cast<uint2*>(&S[tcol][n*64 + dcv*16 + q*4]) = ow;
    }
  }
  __syncthreads();

  // ---- LN2 over O (S cols 0..767); wave handles 4 rows ----
  #pragma unroll
  for (int rq = 0; rq < 4; rq++){
    const int t = wid*4 + rq;
    float v[12];
    #pragma unroll
    for (int j = 0; j < 12; j++) v[j] = bfu2f(S[t][j*64 + lane]);
    float s = 0.f, ss = 0.f;
    #pragma unroll
    for (int j = 0; j < 12; j++){ s += v[j]; ss += v[j]*v[j]; }
    #pragma unroll
    for (int o = 32; o; o >>= 1){ s += __shfl_xor(s, o, 64); ss += __shfl_xor(ss, o, 64); }
    const float mu = s * (1.f/768.f);
    const float rs = rsqrtf(ss*(1.f/768.f) - mu*mu + LNEPS);
    u16* yr = y2 + (rbase + (size_t)t*1024) * C;
    #pragma unroll
    for (int j = 0; j < 12; j++){
      const int c = j*64 + lane;
      yr[c] = f2bfu((v[j]-mu)*rs*w2[c] + b2[c]);
    }
  }
}

extern "C" void kernel_launch(void* const* d_in, const int* in_sizes, int n_in,
                              void* d_out, int out_size, void* d_ws, size_t ws_size,
                              hipStream_t stream){
  const float* x    = (const float*)d_in[0];
  const float* ln1w = (const float*)d_in[1];
  const float* ln1b = (const float*)d_in[2];
  const float* Wqkv = (const float*)d_in[3];
  const float* bqkv = (const float*)d_in[4];
  const float* ln2w = (const float*)d_in[5];
  const float* ln2b = (const float*)d_in[6];
  const float* Wout = (const float*)d_in[7];
  const float* bout = (const float*)d_in[8];
  float* out = (float*)d_out;

  char* ws = (char*)d_ws;
  u16* qkv = (u16*)ws;                       // 32768*2304*2 = 150,994,944 B
  u16* y   = (u16*)(ws + 150994944);         // 32768*768*2  =  50,331,648 B (y1, then y2)
  u16* wq  = (u16*)(ws + 201326592);         // 2304*768*2   =   3,538,944 B
  u16* wo  = (u16*)(ws + 204865536);         // 768*768*2    =   1,179,648 B  (total 206,045,184)

  cvt_bf16<<<(F3*C + 255)/256, 256, 0, stream>>>(Wqkv, wq, F3*C);
  cvt_bf16<<<(C*C + 255)/256, 256, 0, stream>>>(Wout, wo, C*C);
  ln1_kernel<<<MROWS/4, 256, 0, stream>>>(x, ln1w, ln1b, y);
  gemm_bt<0><<<(MROWS/128)*(F3/256), 256, 0, stream>>>(y, wq, bqkv, nullptr, qkv, F3, C);
  attn_ln2<<<2*32*32, 256, 0, stream>>>(qkv, ln2w, ln2b, y);
  gemm_bt<1><<<(MROWS/128)*(C/256), 256, 0, stream>>>(y, wo, bout, x, out, C, C);
}